// Round 1
// 1086.281 us; speedup vs baseline: 3.1031x; 3.1031x over previous
//
#include <hip/hip_runtime.h>

namespace {
constexpr int B = 16, C = 256, N = 16384, K = 64;
constexpr float TEMP = 20.0f, EPS = 1e-6f;
// zT LDS row stride in halfwords: 528 B/row -> 16B-aligned rows, and
// (row*132 + off) mod 32 spreads the 16 k-rows of a b128 fragment read
// evenly across all 8 four-bank groups -> conflict-free ds_read_b128.
constexpr int ZRS = 264;
}

typedef _Float16 f16x8 __attribute__((ext_vector_type(8)));
typedef float f32x4 __attribute__((ext_vector_type(4)));

// Fused EM step. Block = (256 n's of one batch). Thread = (n-pair, k-half):
//   q = tid>>1 in [0,128): n's {n0+q, n0+q+128};  kh = tid&1: k in [kh*32, kh*32+32)
// Phase 1 (VALU): scores -> softmax (TEMP unless FINAL). FINAL: write fp32 out, done.
// Phase 2 (MFMA): z written transposed+fp16 into LDS (reusing the m buffer),
//   S column sums (atomic), then m' = x_tile[256c][256n] . z_tile[256n][64k]
//   on matrix cores: per wave a 64c x 64k tile, K-dim = n in steps of 32.
//   A-frags (x) are n-contiguous fp32 global loads + cvt; B-frags are
//   contiguous fp16 b128 reads from zT. atomicAdd accumulator into mt.
template <bool FINAL>
__global__ __launch_bounds__(256, 2) void kstep_kernel(
    const float* __restrict__ x,   // [B][C][N] fp32
    const float* __restrict__ m,   // [B][C][K] fp32
    float* __restrict__ mt,        // [B][C][K] accum (pre-zeroed)
    float* __restrict__ S,         // [B][K] accum (pre-zeroed)
    float* __restrict__ out) {     // [B][N][K] fp32
  __shared__ float sm[C * K];  // 64 KB: phase1 = m[b], phase2 = zT fp16 [64][ZRS]
  const int tid = threadIdx.x;
  const int b = blockIdx.y;
  const int n0 = blockIdx.x * 256;
  const int kh = tid & 1;
  const int q = tid >> 1;

  {  // stage m[b] -> LDS (coalesced float4)
    const float4* src = (const float4*)(m + (size_t)b * C * K);
    float4* dst = (float4*)sm;
#pragma unroll
    for (int i = 0; i < 16; ++i) dst[tid + 256 * i] = src[tid + 256 * i];
  }
  __syncthreads();

  // ---- phase 1: scores ----
  float a0[32], a1[32];
#pragma unroll
  for (int i = 0; i < 32; ++i) { a0[i] = 0.f; a1[i] = 0.f; }

  const float* xb = x + (size_t)b * C * N + n0 + q;
  const float4* sm4 = (const float4*)sm;
  for (int c = 0; c < C; ++c) {
    float x0 = xb[(size_t)c * N];        // coalesced across lanes
    float x1 = xb[(size_t)c * N + 128];
#pragma unroll
    for (int j = 0; j < 8; ++j) {
      float4 mv = sm4[c * 16 + kh * 8 + j];  // 2 distinct addrs/wave -> broadcast
      a0[4 * j + 0] += x0 * mv.x; a0[4 * j + 1] += x0 * mv.y;
      a0[4 * j + 2] += x0 * mv.z; a0[4 * j + 3] += x0 * mv.w;
      a1[4 * j + 0] += x1 * mv.x; a1[4 * j + 1] += x1 * mv.y;
      a1[4 * j + 2] += x1 * mv.z; a1[4 * j + 3] += x1 * mv.w;
    }
  }

  // ---- softmax over k (pairwise across tid^1 which holds the other k-half) ----
  const float sc = FINAL ? 1.0f : TEMP;  // final einsum has NO temperature
  float mx0 = -1e30f, mx1 = -1e30f;
#pragma unroll
  for (int i = 0; i < 32; ++i) {
    a0[i] *= sc; a1[i] *= sc;
    mx0 = fmaxf(mx0, a0[i]); mx1 = fmaxf(mx1, a1[i]);
  }
  mx0 = fmaxf(mx0, __shfl_xor(mx0, 1));
  mx1 = fmaxf(mx1, __shfl_xor(mx1, 1));
  float s0 = 0.f, s1 = 0.f;
#pragma unroll
  for (int i = 0; i < 32; ++i) {
    a0[i] = __expf(a0[i] - mx0); s0 += a0[i];
    a1[i] = __expf(a1[i] - mx1); s1 += a1[i];
  }
  s0 += __shfl_xor(s0, 1);
  s1 += __shfl_xor(s1, 1);
  const float i0 = 1.0f / s0, i1 = 1.0f / s1;
#pragma unroll
  for (int i = 0; i < 32; ++i) { a0[i] *= i0; a1[i] *= i1; }

  if (FINAL) {
    float4* o0 = (float4*)(out + ((size_t)b * N + n0 + q) * K + kh * 32);
    float4* o1 = (float4*)(out + ((size_t)b * N + n0 + q + 128) * K + kh * 32);
#pragma unroll
    for (int g = 0; g < 8; ++g) {
      o0[g] = make_float4(a0[4 * g], a0[4 * g + 1], a0[4 * g + 2], a0[4 * g + 3]);
      o1[g] = make_float4(a1[4 * g], a1[4 * g + 1], a1[4 * g + 2], a1[4 * g + 3]);
    }
    return;
  }

  // ---- phase 2 ----
  __syncthreads();  // everyone done reading sm as m
  _Float16* zt = (_Float16*)sm;  // zT fp16 [k=64][n=256], row stride ZRS
  {
#pragma unroll
    for (int i = 0; i < 32; ++i) {
      const int k = kh * 32 + i;
      zt[k * ZRS + q] = (_Float16)a0[i];         // local n = q
      zt[k * ZRS + 128 + q] = (_Float16)a1[i];   // local n = q+128
    }
  }
  __syncthreads();

  {  // S[b,k] += sum over this block's n of z; thread = (k, n-quarter)
    const int k = tid & 63, qt = tid >> 6;
    float s = 0.f;
#pragma unroll
    for (int j = 0; j < 8; ++j) {
      f16x8 v = *(const f16x8*)(zt + k * ZRS + qt * 64 + j * 8);
#pragma unroll
      for (int e = 0; e < 8; ++e) s += (float)v[e];
    }
    atomicAdd(&S[b * K + k], s);
  }

  // ---- MFMA: m'[c][k] += sum_n x[c][n] * z[n][k] ----
  // wave w owns c in [w*64, w*64+64), all 64 k. 16 mfma_f32_16x16x32_f16 per
  // k-step (4 c-subtiles x 4 k-subtiles), 8 k-steps cover n=256.
  const int w = tid >> 6;
  const int lane = tid & 63;
  const int lr = lane & 15, lh = lane >> 4;
  const int cbase = w * 64;
  f32x4 acc[4][4];
#pragma unroll
  for (int mi = 0; mi < 4; ++mi)
#pragma unroll
    for (int ni = 0; ni < 4; ++ni) acc[mi][ni] = (f32x4){0.f, 0.f, 0.f, 0.f};

  const float* xw = x + (size_t)b * C * N + n0;
  for (int ks = 0; ks < 8; ++ks) {
    const int np = ks * 32 + lh * 8;  // n-offset of this lane's 8 A/B elements
    f16x8 af[4];
#pragma unroll
    for (int mi = 0; mi < 4; ++mi) {
      // A[c][n]: row c = cbase+mi*16+lr, 8 consecutive n -> two float4 loads.
      // Lanes lh=0..3 of one row cover one full 128B line (u+v) -> clean L1.
      const float* p = xw + (size_t)(cbase + mi * 16 + lr) * N + np;
      const float4 u = *(const float4*)p;
      const float4 v = *(const float4*)(p + 4);
      f16x8 t;
      t[0] = (_Float16)u.x; t[1] = (_Float16)u.y;
      t[2] = (_Float16)u.z; t[3] = (_Float16)u.w;
      t[4] = (_Float16)v.x; t[5] = (_Float16)v.y;
      t[6] = (_Float16)v.z; t[7] = (_Float16)v.w;
      af[mi] = t;
    }
#pragma unroll
    for (int ni = 0; ni < 4; ++ni) {
      // B[n][k]: lane needs 8 consecutive n for k = ni*16+lr -> zT row read.
      const f16x8 bf = *(const f16x8*)(zt + (ni * 16 + lr) * ZRS + np);
#pragma unroll
      for (int mi = 0; mi < 4; ++mi)
        acc[mi][ni] =
            __builtin_amdgcn_mfma_f32_16x16x32_f16(af[mi], bf, acc[mi][ni], 0, 0, 0);
    }
  }

  // D layout (16x16): col = lane&15 (k), row = (lane>>4)*4 + reg (c).
#pragma unroll
  for (int mi = 0; mi < 4; ++mi)
#pragma unroll
    for (int ni = 0; ni < 4; ++ni) {
      const int k = ni * 16 + lr;
#pragma unroll
      for (int r = 0; r < 4; ++r) {
        const int c = cbase + mi * 16 + lh * 4 + r;
        atomicAdd(&mt[((size_t)b * C + c) * K + k], acc[mi][ni][r]);
      }
    }
}

// m[b,c,k] = l2norm_c( mt[b,:,k] * l1scale[k] );  l1scale = 1/(EPS + S[b,k])
__global__ __launch_bounds__(64) void kl2_kernel(const float* __restrict__ mt,
                                                 const float* __restrict__ S,
                                                 float* __restrict__ m) {
  const int k = blockIdx.x, b = blockIdx.y, lane = threadIdx.x;
  const float s = 1.0f / (EPS + S[b * K + k]);
  float v[4];
  float ss = 0.f;
#pragma unroll
  for (int i = 0; i < 4; ++i) {
    v[i] = mt[((size_t)b * C + lane + 64 * i) * K + k] * s;
    ss += v[i] * v[i];
  }
#pragma unroll
  for (int off = 32; off >= 1; off >>= 1) ss += __shfl_xor(ss, off);
  const float inv = 1.0f / (EPS + sqrtf(ss));
#pragma unroll
  for (int i = 0; i < 4; ++i)
    m[((size_t)b * C + lane + 64 * i) * K + k] = v[i] * inv;
}

// init: m[b,c,k] = mu[c,k] (fp32 broadcast over b)
__global__ __launch_bounds__(256) void kinit_kernel(
    const float* __restrict__ mu, float* __restrict__ m) {
  const int idx = blockIdx.x * 256 + threadIdx.x;
  m[idx] = mu[idx & (C * K - 1)];
}

__global__ __launch_bounds__(256) void kzero_kernel(float* __restrict__ p, int ntot) {
  const int i = blockIdx.x * 256 + threadIdx.x;
  if (i < ntot) p[i] = 0.f;
}

extern "C" void kernel_launch(void* const* d_in, const int* in_sizes, int n_in,
                              void* d_out, int out_size, void* d_ws,
                              size_t ws_size, hipStream_t stream) {
  const float* x = (const float*)d_in[0];   // fp32 [B][C][N]
  const float* mu = (const float*)d_in[1];  // fp32 [1][C][K]
  float* out = (float*)d_out;               // fp32 [B][N][K]

  // ws layout (fp32): m[B*C*K] | mt[B*C*K] | S[B*K]  (~2.01 MB total)
  float* m = (float*)d_ws;
  float* mt = m + (size_t)B * C * K;
  float* S = mt + (size_t)B * C * K;
  const int nz = B * C * K + B * K;  // mt + S contiguous

  kinit_kernel<<<B * C * K / 256, 256, 0, stream>>>(mu, m);
  for (int step = 0; step < 3; ++step) {
    kzero_kernel<<<(nz + 255) / 256, 256, 0, stream>>>(mt, nz);
    kstep_kernel<false><<<dim3(N / 256, B), 256, 0, stream>>>(x, m, mt, S, nullptr);
    kl2_kernel<<<dim3(K, B), 64, 0, stream>>>(mt, S, m);
  }
  kstep_kernel<true><<<dim3(N / 256, B), 256, 0, stream>>>(x, m, nullptr, nullptr, out);
}

// Round 2
// 766.896 us; speedup vs baseline: 4.3954x; 1.4165x over previous
//
#include <hip/hip_runtime.h>
#include <cstdint>

namespace {
constexpr int B = 16, C = 256, N = 16384, K = 64;
constexpr float TEMP = 20.0f, EPS = 1e-6f;
// zT row stride in halfwords: 528 B/row, 16B-aligned, spreads b128 reads.
constexpr int ZRS = 264;
constexpr int CCH = 32;            // c per phase-1 chunk
constexpr int NCHUNK = C / CCH;    // 8
// phase-1 LDS (u32 units): xT hi/lo [256 n][16 u32], mT hi/lo [64 k][16 u32].
constexpr int XTH = 0, XTL = 4096, MTH = 8192, MTL = 9216;
constexpr int SMU_SIZE = 10240;    // 40 KB (phase 2 zT = 33 KB fits at offset 0)
}

typedef _Float16 f16x8 __attribute__((ext_vector_type(8)));
typedef float f32x4 __attribute__((ext_vector_type(4)));

__device__ __forceinline__ uint32_t pack2(_Float16 a, _Float16 b) {
  union { _Float16 h[2]; uint32_t u; } t;
  t.h[0] = a; t.h[1] = b;
  return t.u;
}

// Slot-swizzled u32 index into a row-major [rows][16 u32] LDS tile.
// slot (16B unit) ^= (row>>1)&3: b128 writes (lane=row, slot fixed) and b128
// fragment reads (row=base+lr, slot=lh) both land 8 lanes per slot -> uniform
// over all 32 banks -> conflict-free.
__device__ __forceinline__ int swz(int row, int slot) {
  return row * 16 + 4 * (slot ^ ((row >> 1) & 3));
}

// Fused EM step. Block = 256 n's of one batch, 4 waves.
// Phase 1 (MFMA): Z[256n][64k] = xT[256n][256c] . m[256c][64k], c chunked by 32.
//   x and m are split fp16 hi+lo (z = xh*mh + xh*ml + xl*mh; lo*lo dropped)
//   -> ~fp32-accurate scores. Wave w owns n in [w*64, w*64+64), all 64 k.
//   Staging transposes x: thread t owns row n=t, reads x[c][n0+t] (coalesced
//   column-walk), packs fp16 pairs, b128-writes swizzled slots.
// Softmax in MFMA D-layout: row n = w*64+mi*16+lh*4+r holds its 64 k across
//   {4 regs (ni)} x {16 lanes (lr)} -> 4-wide local + shfl_xor(1,2,4,8) reduce.
// FINAL: scatter-store fp32 out (wave instr = 4 rows x 64B segments), done.
// Phase 2 (MFMA, unchanged from prev round): zT fp16 in LDS, S col-sums,
//   m'[c][k] += x[c][n] . z[n][k] with n contiguous from global, atomics to mt.
template <bool FINAL>
__global__ __launch_bounds__(256, 2) void kstep_kernel(
    const float* __restrict__ x,   // [B][C][N] fp32
    const float* __restrict__ m,   // [B][C][K] fp32
    float* __restrict__ mt,        // [B][C][K] accum (pre-zeroed)
    float* __restrict__ S,         // [B][K] accum (pre-zeroed)
    float* __restrict__ out) {     // [B][N][K] fp32
  __shared__ __attribute__((aligned(16))) uint32_t smu[SMU_SIZE];
  const int tid = threadIdx.x;
  const int b = blockIdx.y;
  const int n0 = blockIdx.x * 256;
  const int w = tid >> 6;
  const int lane = tid & 63;
  const int lr = lane & 15, lh = lane >> 4;

  // ---- phase 1: scores via MFMA ----
  f32x4 acc[4][4];
#pragma unroll
  for (int mi = 0; mi < 4; ++mi)
#pragma unroll
    for (int ni = 0; ni < 4; ++ni) acc[mi][ni] = (f32x4){0.f, 0.f, 0.f, 0.f};

  const float* xcol = x + (size_t)b * C * N + n0 + tid;  // stride N per c

  for (int ci = 0; ci < NCHUNK; ++ci) {
    const int c0 = ci * CCH;
    __syncthreads();  // prev chunk's fragment reads done before overwrite

    // x-stage: thread owns xT row n=tid; slot i holds c = c0+8i .. +7
#pragma unroll
    for (int i = 0; i < 4; ++i) {
      float v[8];
#pragma unroll
      for (int j = 0; j < 8; ++j) v[j] = xcol[(size_t)(c0 + 8 * i + j) * N];
      uint32_t hp[4], lp[4];
#pragma unroll
      for (int jj = 0; jj < 4; ++jj) {
        const _Float16 h0 = (_Float16)v[2 * jj], h1 = (_Float16)v[2 * jj + 1];
        const _Float16 l0 = (_Float16)(v[2 * jj] - (float)h0);
        const _Float16 l1 = (_Float16)(v[2 * jj + 1] - (float)h1);
        hp[jj] = pack2(h0, h1);
        lp[jj] = pack2(l0, l1);
      }
      const int e = swz(tid, i);
      *(uint4*)&smu[XTH + e] = make_uint4(hp[0], hp[1], hp[2], hp[3]);
      *(uint4*)&smu[XTL + e] = make_uint4(lp[0], lp[1], lp[2], lp[3]);
    }
    {  // m-stage: thread = (k=lane, slot=w); mT row k, c = c0+8w .. +7
      float v[8];
#pragma unroll
      for (int j = 0; j < 8; ++j)
        v[j] = m[((size_t)b * C + c0 + 8 * w + j) * K + lane];
      uint32_t hp[4], lp[4];
#pragma unroll
      for (int jj = 0; jj < 4; ++jj) {
        const _Float16 h0 = (_Float16)v[2 * jj], h1 = (_Float16)v[2 * jj + 1];
        const _Float16 l0 = (_Float16)(v[2 * jj] - (float)h0);
        const _Float16 l1 = (_Float16)(v[2 * jj + 1] - (float)h1);
        hp[jj] = pack2(h0, h1);
        lp[jj] = pack2(l0, l1);
      }
      const int e = swz(lane, w);
      *(uint4*)&smu[MTH + e] = make_uint4(hp[0], hp[1], hp[2], hp[3]);
      *(uint4*)&smu[MTL + e] = make_uint4(lp[0], lp[1], lp[2], lp[3]);
    }
    __syncthreads();

    // fragments + 48 MFMA (hh, hl, lh)
    f16x8 ah[4], al[4], bh[4], bl[4];
#pragma unroll
    for (int t = 0; t < 4; ++t) {
      const int ea = swz(w * 64 + t * 16 + lr, lh);
      ah[t] = *(const f16x8*)&smu[XTH + ea];
      al[t] = *(const f16x8*)&smu[XTL + ea];
      const int eb = swz(t * 16 + lr, lh);
      bh[t] = *(const f16x8*)&smu[MTH + eb];
      bl[t] = *(const f16x8*)&smu[MTL + eb];
    }
#pragma unroll
    for (int ni = 0; ni < 4; ++ni)
#pragma unroll
      for (int mi = 0; mi < 4; ++mi) {
        acc[mi][ni] =
            __builtin_amdgcn_mfma_f32_16x16x32_f16(ah[mi], bh[ni], acc[mi][ni], 0, 0, 0);
        acc[mi][ni] =
            __builtin_amdgcn_mfma_f32_16x16x32_f16(ah[mi], bl[ni], acc[mi][ni], 0, 0, 0);
        acc[mi][ni] =
            __builtin_amdgcn_mfma_f32_16x16x32_f16(al[mi], bh[ni], acc[mi][ni], 0, 0, 0);
      }
  }

  // ---- softmax over k, in D-layout ----
  // Row n = w*64 + mi*16 + lh*4 + r; its 64 k's = {ni*16+lr} over 16 lr-lanes.
  const float sc = FINAL ? 1.0f : TEMP;  // final einsum has NO temperature
#pragma unroll
  for (int mi = 0; mi < 4; ++mi)
#pragma unroll
    for (int r = 0; r < 4; ++r) {
      float v0 = acc[mi][0][r] * sc, v1 = acc[mi][1][r] * sc;
      float v2 = acc[mi][2][r] * sc, v3 = acc[mi][3][r] * sc;
      float mx = fmaxf(fmaxf(v0, v1), fmaxf(v2, v3));
      mx = fmaxf(mx, __shfl_xor(mx, 1));
      mx = fmaxf(mx, __shfl_xor(mx, 2));
      mx = fmaxf(mx, __shfl_xor(mx, 4));
      mx = fmaxf(mx, __shfl_xor(mx, 8));
      v0 = __expf(v0 - mx); v1 = __expf(v1 - mx);
      v2 = __expf(v2 - mx); v3 = __expf(v3 - mx);
      float s = v0 + v1 + v2 + v3;
      s += __shfl_xor(s, 1);
      s += __shfl_xor(s, 2);
      s += __shfl_xor(s, 4);
      s += __shfl_xor(s, 8);
      const float inv = 1.0f / s;
      acc[mi][0][r] = v0 * inv; acc[mi][1][r] = v1 * inv;
      acc[mi][2][r] = v2 * inv; acc[mi][3][r] = v3 * inv;
    }

  if (FINAL) {
    float* ob = out + ((size_t)b * N + n0 + w * 64) * K;
#pragma unroll
    for (int mi = 0; mi < 4; ++mi)
#pragma unroll
      for (int r = 0; r < 4; ++r) {
        const int row = mi * 16 + lh * 4 + r;
#pragma unroll
        for (int ni = 0; ni < 4; ++ni)
          ob[(size_t)row * K + ni * 16 + lr] = acc[mi][ni][r];
      }
    return;
  }

  // ---- phase 2 ----
  __syncthreads();  // all waves done reading xT/mT
  _Float16* zt = (_Float16*)smu;  // zT fp16 [k=64][n=256], row stride ZRS
#pragma unroll
  for (int mi = 0; mi < 4; ++mi)
#pragma unroll
    for (int ni = 0; ni < 4; ++ni)
#pragma unroll
      for (int r = 0; r < 4; ++r)
        zt[(ni * 16 + lr) * ZRS + w * 64 + mi * 16 + lh * 4 + r] =
            (_Float16)acc[mi][ni][r];
  __syncthreads();

  {  // S[b,k] += sum over this block's n of z; thread = (k, n-quarter)
    const int k = tid & 63, qt = tid >> 6;
    float s = 0.f;
#pragma unroll
    for (int j = 0; j < 8; ++j) {
      f16x8 v = *(const f16x8*)(zt + k * ZRS + qt * 64 + j * 8);
#pragma unroll
      for (int e = 0; e < 8; ++e) s += (float)v[e];
    }
    atomicAdd(&S[b * K + k], s);
  }

  // MFMA: m'[c][k] += sum_n x[c][n] * z[n][k]; wave w owns c in [w*64, w*64+64).
  const int cbase = w * 64;
  f32x4 acc2[4][4];
#pragma unroll
  for (int mi = 0; mi < 4; ++mi)
#pragma unroll
    for (int ni = 0; ni < 4; ++ni) acc2[mi][ni] = (f32x4){0.f, 0.f, 0.f, 0.f};

  const float* xw = x + (size_t)b * C * N + n0;
  for (int ks = 0; ks < 8; ++ks) {
    const int np = ks * 32 + lh * 8;  // n-offset of this lane's 8 A/B elements
    f16x8 af[4];
#pragma unroll
    for (int mi = 0; mi < 4; ++mi) {
      // A[c][n]: row c = cbase+mi*16+lr, 8 consecutive n -> two float4 loads.
      const float* p = xw + (size_t)(cbase + mi * 16 + lr) * N + np;
      const float4 u = *(const float4*)p;
      const float4 v = *(const float4*)(p + 4);
      f16x8 t;
      t[0] = (_Float16)u.x; t[1] = (_Float16)u.y;
      t[2] = (_Float16)u.z; t[3] = (_Float16)u.w;
      t[4] = (_Float16)v.x; t[5] = (_Float16)v.y;
      t[6] = (_Float16)v.z; t[7] = (_Float16)v.w;
      af[mi] = t;
    }
#pragma unroll
    for (int ni = 0; ni < 4; ++ni) {
      // B[n][k]: lane needs 8 consecutive n for k = ni*16+lr -> zT row read.
      const f16x8 bf = *(const f16x8*)(zt + (ni * 16 + lr) * ZRS + np);
#pragma unroll
      for (int mi = 0; mi < 4; ++mi)
        acc2[mi][ni] =
            __builtin_amdgcn_mfma_f32_16x16x32_f16(af[mi], bf, acc2[mi][ni], 0, 0, 0);
    }
  }

  // D layout (16x16): col = lane&15 (k), row = (lane>>4)*4 + reg (c).
#pragma unroll
  for (int mi = 0; mi < 4; ++mi)
#pragma unroll
    for (int ni = 0; ni < 4; ++ni) {
      const int k = ni * 16 + lr;
#pragma unroll
      for (int r = 0; r < 4; ++r) {
        const int c = cbase + mi * 16 + lh * 4 + r;
        atomicAdd(&mt[((size_t)b * C + c) * K + k], acc2[mi][ni][r]);
      }
    }
}

// m[b,c,k] = l2norm_c( mt[b,:,k] * l1scale[k] );  l1scale = 1/(EPS + S[b,k])
__global__ __launch_bounds__(64) void kl2_kernel(const float* __restrict__ mt,
                                                 const float* __restrict__ S,
                                                 float* __restrict__ m) {
  const int k = blockIdx.x, b = blockIdx.y, lane = threadIdx.x;
  const float s = 1.0f / (EPS + S[b * K + k]);
  float v[4];
  float ss = 0.f;
#pragma unroll
  for (int i = 0; i < 4; ++i) {
    v[i] = mt[((size_t)b * C + lane + 64 * i) * K + k] * s;
    ss += v[i] * v[i];
  }
#pragma unroll
  for (int off = 32; off >= 1; off >>= 1) ss += __shfl_xor(ss, off);
  const float inv = 1.0f / (EPS + sqrtf(ss));
#pragma unroll
  for (int i = 0; i < 4; ++i)
    m[((size_t)b * C + lane + 64 * i) * K + k] = v[i] * inv;
}

// init: m[b,c,k] = mu[c,k] (fp32 broadcast over b)
__global__ __launch_bounds__(256) void kinit_kernel(
    const float* __restrict__ mu, float* __restrict__ m) {
  const int idx = blockIdx.x * 256 + threadIdx.x;
  m[idx] = mu[idx & (C * K - 1)];
}

__global__ __launch_bounds__(256) void kzero_kernel(float* __restrict__ p, int ntot) {
  const int i = blockIdx.x * 256 + threadIdx.x;
  if (i < ntot) p[i] = 0.f;
}

extern "C" void kernel_launch(void* const* d_in, const int* in_sizes, int n_in,
                              void* d_out, int out_size, void* d_ws,
                              size_t ws_size, hipStream_t stream) {
  const float* x = (const float*)d_in[0];   // fp32 [B][C][N]
  const float* mu = (const float*)d_in[1];  // fp32 [1][C][K]
  float* out = (float*)d_out;               // fp32 [B][N][K]

  // ws layout (fp32): m[B*C*K] | mt[B*C*K] | S[B*K]  (~2.01 MB total)
  float* m = (float*)d_ws;
  float* mt = m + (size_t)B * C * K;
  float* S = mt + (size_t)B * C * K;
  const int nz = B * C * K + B * K;  // mt + S contiguous

  kinit_kernel<<<B * C * K / 256, 256, 0, stream>>>(mu, m);
  for (int step = 0; step < 3; ++step) {
    kzero_kernel<<<(nz + 255) / 256, 256, 0, stream>>>(mt, nz);
    kstep_kernel<false><<<dim3(N / 256, B), 256, 0, stream>>>(x, m, mt, S, nullptr);
    kl2_kernel<<<dim3(K, B), 64, 0, stream>>>(mt, S, m);
  }
  kstep_kernel<true><<<dim3(N / 256, B), 256, 0, stream>>>(x, m, nullptr, nullptr, out);
}

// Round 3
// 732.343 us; speedup vs baseline: 4.6028x; 1.0472x over previous
//
#include <hip/hip_runtime.h>
#include <cstdint>

namespace {
constexpr int B = 16, C = 256, N = 16384, K = 64;
constexpr float TEMP = 20.0f, EPS = 1e-6f;
// zT row stride in halfwords: 528 B/row, 16B-aligned, spreads b128 reads.
constexpr int ZRS = 264;
constexpr int CCH = 32;            // c per phase-1 chunk
constexpr int NCHUNK = C / CCH;    // 8
// phase-1 LDS (u32 units): xT hi/lo [256 n][16 u32], mT hi/lo [64 k][16 u32].
constexpr int XTH = 0, XTL = 4096, MTH = 8192, MTL = 9216;
constexpr int SMU_SIZE = 10240;    // 40 KB (phase 2 zT = 33 KB fits at offset 0)
}

typedef _Float16 f16x8 __attribute__((ext_vector_type(8)));
typedef float f32x4 __attribute__((ext_vector_type(4)));

__device__ __forceinline__ uint32_t pack2(_Float16 a, _Float16 b) {
  union { _Float16 h[2]; uint32_t u; } t;
  t.h[0] = a; t.h[1] = b;
  return t.u;
}

// Slot-swizzled u32 index into a row-major [rows][16 u32] LDS tile.
// slot (16B unit) ^= (row>>1)&3: b128 writes and b128 fragment reads both land
// 8 lanes per slot -> uniform over all 32 banks -> conflict-free.
__device__ __forceinline__ int swz(int row, int slot) {
  return row * 16 + 4 * (slot ^ ((row >> 1) & 3));
}

// Fused EM step. Block = 256 n's of one batch, 4 waves.
// Phase 1 (MFMA): Z[256n][64k] = xT[256n][256c] . m[256c][64k], c chunked by 32,
//   x/m split fp16 hi+lo (hh+hl+lh MFMAs) -> ~fp32-accurate scores.
//   SOFTWARE PIPELINED: chunk ci+1's 40 global dwords are issued right after
//   barrier B of chunk ci, so they stay in flight across frag reads + 48 MFMAs;
//   the vmcnt(0) drain of the NEXT iteration's __syncthreads is the wait point.
// Softmax in MFMA D-layout (4 regs x 16 lr-lanes per row, shfl_xor reduce).
// FINAL: scatter-store fp32 out, done.
// Phase 2 (MFMA): zT fp16 in LDS, S col-sums, m'[c][k] += x[c][n].z[n][k],
//   ks-loop prefetches next 8 float4 x-loads (L2/L3-hot) under the MFMAs.
template <bool FINAL>
__global__ __launch_bounds__(256, 2) void kstep_kernel(
    const float* __restrict__ x,   // [B][C][N] fp32
    const float* __restrict__ m,   // [B][C][K] fp32 (or mu with mstride=0)
    const int mstride,             // 0 (step 0: mu broadcast) or C*K
    float* __restrict__ mt,        // [B][C][K] accum (pre-zeroed)
    float* __restrict__ S,         // [B][K] accum (pre-zeroed)
    float* __restrict__ out) {     // [B][N][K] fp32
  __shared__ __attribute__((aligned(16))) uint32_t smu[SMU_SIZE];
  const int tid = threadIdx.x;
  const int b = blockIdx.y;
  const int n0 = blockIdx.x * 256;
  const int w = tid >> 6;
  const int lane = tid & 63;
  const int lr = lane & 15, lh = lane >> 4;

  // ---- phase 1: scores via MFMA, reg-prefetch pipelined ----
  f32x4 acc[4][4];
#pragma unroll
  for (int mi = 0; mi < 4; ++mi)
#pragma unroll
    for (int ni = 0; ni < 4; ++ni) acc[mi][ni] = (f32x4){0.f, 0.f, 0.f, 0.f};

  const float* xcol = x + (size_t)b * C * N + n0 + tid;  // stride N per c
  const float* mrow = m + (size_t)b * mstride + lane;    // k = lane

  float xv[32], mv[8];  // prefetch registers for one chunk
#define LOAD_CHUNK(ci)                                                    \
  {                                                                       \
    const int cc = (ci) * CCH;                                            \
    _Pragma("unroll") for (int i = 0; i < 32; ++i)                        \
        xv[i] = xcol[(size_t)(cc + i) * N];                               \
    _Pragma("unroll") for (int j = 0; j < 8; ++j)                         \
        mv[j] = mrow[(size_t)(cc + 8 * w + j) * K];                       \
  }

  LOAD_CHUNK(0);

  for (int ci = 0; ci < NCHUNK; ++ci) {
    // (A) prev chunk's fragment reads done; drains vmcnt -> xv/mv ready.
    __syncthreads();

    // pack xv -> xT hi/lo (row n=tid, 4 swizzled b128 writes each)
#pragma unroll
    for (int i = 0; i < 4; ++i) {
      uint32_t hp[4], lp[4];
#pragma unroll
      for (int jj = 0; jj < 4; ++jj) {
        const float v0 = xv[8 * i + 2 * jj], v1 = xv[8 * i + 2 * jj + 1];
        const _Float16 h0 = (_Float16)v0, h1 = (_Float16)v1;
        const _Float16 l0 = (_Float16)(v0 - (float)h0);
        const _Float16 l1 = (_Float16)(v1 - (float)h1);
        hp[jj] = pack2(h0, h1);
        lp[jj] = pack2(l0, l1);
      }
      const int e = swz(tid, i);
      *(uint4*)&smu[XTH + e] = make_uint4(hp[0], hp[1], hp[2], hp[3]);
      *(uint4*)&smu[XTL + e] = make_uint4(lp[0], lp[1], lp[2], lp[3]);
    }
    {  // pack mv -> mT hi/lo (row k=lane, slot w)
      uint32_t hp[4], lp[4];
#pragma unroll
      for (int jj = 0; jj < 4; ++jj) {
        const float v0 = mv[2 * jj], v1 = mv[2 * jj + 1];
        const _Float16 h0 = (_Float16)v0, h1 = (_Float16)v1;
        const _Float16 l0 = (_Float16)(v0 - (float)h0);
        const _Float16 l1 = (_Float16)(v1 - (float)h1);
        hp[jj] = pack2(h0, h1);
        lp[jj] = pack2(l0, l1);
      }
      const int e = swz(lane, w);
      *(uint4*)&smu[MTH + e] = make_uint4(hp[0], hp[1], hp[2], hp[3]);
      *(uint4*)&smu[MTL + e] = make_uint4(lp[0], lp[1], lp[2], lp[3]);
    }
    __syncthreads();  // (B) writes visible

    // issue next chunk's loads NOW -> in flight across frags+MFMA, drained at (A)
    if (ci + 1 < NCHUNK) LOAD_CHUNK(ci + 1);

    // fragments + 48 MFMA (hh, hl, lh)
    f16x8 ah[4], al[4];
#pragma unroll
    for (int t = 0; t < 4; ++t) {
      const int ea = swz(w * 64 + t * 16 + lr, lh);
      ah[t] = *(const f16x8*)&smu[XTH + ea];
      al[t] = *(const f16x8*)&smu[XTL + ea];
    }
#pragma unroll
    for (int ni = 0; ni < 4; ++ni) {
      const int eb = swz(ni * 16 + lr, lh);
      const f16x8 bh = *(const f16x8*)&smu[MTH + eb];
      const f16x8 bl = *(const f16x8*)&smu[MTL + eb];
#pragma unroll
      for (int mi = 0; mi < 4; ++mi) {
        acc[mi][ni] =
            __builtin_amdgcn_mfma_f32_16x16x32_f16(ah[mi], bh, acc[mi][ni], 0, 0, 0);
        acc[mi][ni] =
            __builtin_amdgcn_mfma_f32_16x16x32_f16(ah[mi], bl, acc[mi][ni], 0, 0, 0);
        acc[mi][ni] =
            __builtin_amdgcn_mfma_f32_16x16x32_f16(al[mi], bh, acc[mi][ni], 0, 0, 0);
      }
    }
  }
#undef LOAD_CHUNK

  // ---- softmax over k, in D-layout ----
  const float sc = FINAL ? 1.0f : TEMP;  // final einsum has NO temperature
#pragma unroll
  for (int mi = 0; mi < 4; ++mi)
#pragma unroll
    for (int r = 0; r < 4; ++r) {
      float v0 = acc[mi][0][r] * sc, v1 = acc[mi][1][r] * sc;
      float v2 = acc[mi][2][r] * sc, v3 = acc[mi][3][r] * sc;
      float mx = fmaxf(fmaxf(v0, v1), fmaxf(v2, v3));
      mx = fmaxf(mx, __shfl_xor(mx, 1));
      mx = fmaxf(mx, __shfl_xor(mx, 2));
      mx = fmaxf(mx, __shfl_xor(mx, 4));
      mx = fmaxf(mx, __shfl_xor(mx, 8));
      v0 = __expf(v0 - mx); v1 = __expf(v1 - mx);
      v2 = __expf(v2 - mx); v3 = __expf(v3 - mx);
      float s = v0 + v1 + v2 + v3;
      s += __shfl_xor(s, 1);
      s += __shfl_xor(s, 2);
      s += __shfl_xor(s, 4);
      s += __shfl_xor(s, 8);
      const float inv = 1.0f / s;
      acc[mi][0][r] = v0 * inv; acc[mi][1][r] = v1 * inv;
      acc[mi][2][r] = v2 * inv; acc[mi][3][r] = v3 * inv;
    }

  if (FINAL) {
    float* ob = out + ((size_t)b * N + n0 + w * 64) * K;
#pragma unroll
    for (int mi = 0; mi < 4; ++mi)
#pragma unroll
      for (int r = 0; r < 4; ++r) {
        const int row = mi * 16 + lh * 4 + r;
#pragma unroll
        for (int ni = 0; ni < 4; ++ni)
          ob[(size_t)row * K + ni * 16 + lr] = acc[mi][ni][r];
      }
    return;
  }

  // ---- phase 2 ----
  __syncthreads();  // all waves done reading xT/mT
  _Float16* zt = (_Float16*)smu;  // zT fp16 [k=64][n=256], row stride ZRS
#pragma unroll
  for (int mi = 0; mi < 4; ++mi)
#pragma unroll
    for (int ni = 0; ni < 4; ++ni)
#pragma unroll
      for (int r = 0; r < 4; ++r)
        zt[(ni * 16 + lr) * ZRS + w * 64 + mi * 16 + lh * 4 + r] =
            (_Float16)acc[mi][ni][r];
  __syncthreads();

  // prefetch ks=0's x rows now (overlaps the S-sum below)
  const int cbase = w * 64;
  const float* xw = x + (size_t)b * C * N + n0;
  float4 cu[4], cv[4];
#define LOAD_KS(ks)                                                         \
  {                                                                         \
    const int np = (ks) * 32 + lh * 8;                                      \
    _Pragma("unroll") for (int mi = 0; mi < 4; ++mi) {                      \
      const float* p = xw + (size_t)(cbase + mi * 16 + lr) * N + np;        \
      cu[mi] = *(const float4*)p;                                           \
      cv[mi] = *(const float4*)(p + 4);                                     \
    }                                                                       \
  }
  LOAD_KS(0);

  {  // S[b,k] += sum over this block's n of z; thread = (k, n-quarter)
    const int k = tid & 63, qt = tid >> 6;
    float s = 0.f;
#pragma unroll
    for (int j = 0; j < 8; ++j) {
      f16x8 v = *(const f16x8*)(zt + k * ZRS + qt * 64 + j * 8);
#pragma unroll
      for (int e = 0; e < 8; ++e) s += (float)v[e];
    }
    atomicAdd(&S[b * K + k], s);
  }

  // MFMA: m'[c][k] += sum_n x[c][n] * z[n][k]; wave w owns c in [cbase, cbase+64)
  f32x4 acc2[4][4];
#pragma unroll
  for (int mi = 0; mi < 4; ++mi)
#pragma unroll
    for (int ni = 0; ni < 4; ++ni) acc2[mi][ni] = (f32x4){0.f, 0.f, 0.f, 0.f};

  for (int ks = 0; ks < 8; ++ks) {
    const int np = ks * 32 + lh * 8;
    f16x8 af[4];
#pragma unroll
    for (int mi = 0; mi < 4; ++mi) {
      f16x8 t;
      t[0] = (_Float16)cu[mi].x; t[1] = (_Float16)cu[mi].y;
      t[2] = (_Float16)cu[mi].z; t[3] = (_Float16)cu[mi].w;
      t[4] = (_Float16)cv[mi].x; t[5] = (_Float16)cv[mi].y;
      t[6] = (_Float16)cv[mi].z; t[7] = (_Float16)cv[mi].w;
      af[mi] = t;
    }
    if (ks + 1 < 8) LOAD_KS(ks + 1);  // in flight under the 16 MFMAs
#pragma unroll
    for (int ni = 0; ni < 4; ++ni) {
      const f16x8 bf = *(const f16x8*)(zt + (ni * 16 + lr) * ZRS + np);
#pragma unroll
      for (int mi = 0; mi < 4; ++mi)
        acc2[mi][ni] =
            __builtin_amdgcn_mfma_f32_16x16x32_f16(af[mi], bf, acc2[mi][ni], 0, 0, 0);
    }
  }
#undef LOAD_KS

  // D layout (16x16): col = lane&15 (k), row = (lane>>4)*4 + reg (c).
#pragma unroll
  for (int mi = 0; mi < 4; ++mi)
#pragma unroll
    for (int ni = 0; ni < 4; ++ni) {
      const int k = ni * 16 + lr;
#pragma unroll
      for (int r = 0; r < 4; ++r) {
        const int c = cbase + mi * 16 + lh * 4 + r;
        atomicAdd(&mt[((size_t)b * C + c) * K + k], acc2[mi][ni][r]);
      }
    }
}

// m[b,c,k] = l2norm_c( mt[b,:,k] * l1scale[k] );  l1scale = 1/(EPS + S[b,k])
// Also re-zeroes mt and S for the next EM step (saves the kzero launch).
__global__ __launch_bounds__(64) void kl2_kernel(float* __restrict__ mt,
                                                 float* __restrict__ S,
                                                 float* __restrict__ m) {
  const int k = blockIdx.x, b = blockIdx.y, lane = threadIdx.x;
  const float s = 1.0f / (EPS + S[b * K + k]);
  float v[4];
  float ss = 0.f;
#pragma unroll
  for (int i = 0; i < 4; ++i) {
    const size_t idx = ((size_t)b * C + lane + 64 * i) * K + k;
    v[i] = mt[idx] * s;
    mt[idx] = 0.f;  // re-zero for next step's atomics
    ss += v[i] * v[i];
  }
  if (lane == 0) S[b * K + k] = 0.f;
#pragma unroll
  for (int off = 32; off >= 1; off >>= 1) ss += __shfl_xor(ss, off);
  const float inv = 1.0f / (EPS + sqrtf(ss));
#pragma unroll
  for (int i = 0; i < 4; ++i)
    m[((size_t)b * C + lane + 64 * i) * K + k] = v[i] * inv;
}

__global__ __launch_bounds__(256) void kzero_kernel(float* __restrict__ p, int ntot) {
  const int i = blockIdx.x * 256 + threadIdx.x;
  if (i < ntot) p[i] = 0.f;
}

extern "C" void kernel_launch(void* const* d_in, const int* in_sizes, int n_in,
                              void* d_out, int out_size, void* d_ws,
                              size_t ws_size, hipStream_t stream) {
  const float* x = (const float*)d_in[0];   // fp32 [B][C][N]
  const float* mu = (const float*)d_in[1];  // fp32 [1][C][K]
  float* out = (float*)d_out;               // fp32 [B][N][K]

  // ws layout (fp32): m[B*C*K] | mt[B*C*K] | S[B*K]  (~2.01 MB total)
  float* m = (float*)d_ws;
  float* mt = m + (size_t)B * C * K;
  float* S = mt + (size_t)B * C * K;
  const int nz = B * C * K + B * K;  // mt + S contiguous

  kzero_kernel<<<(nz + 255) / 256, 256, 0, stream>>>(mt, nz);
  for (int step = 0; step < 3; ++step) {
    // step 0 reads mu directly (broadcast over b via mstride=0) - no kinit.
    const float* msrc = step == 0 ? mu : m;
    const int mstride = step == 0 ? 0 : C * K;
    kstep_kernel<false><<<dim3(N / 256, B), 256, 0, stream>>>(x, msrc, mstride,
                                                              mt, S, nullptr);
    kl2_kernel<<<dim3(K, B), 64, 0, stream>>>(mt, S, m);  // + re-zero mt,S
  }
  kstep_kernel<true><<<dim3(N / 256, B), 256, 0, stream>>>(x, m, C * K, nullptr,
                                                           nullptr, out);
}